// Round 1
// baseline (1851.671 us; speedup 1.0000x reference)
//
#include <hip/hip_runtime.h>
#include <hip/hip_bf16.h>
#include <math.h>
#include <stdint.h>

typedef unsigned int u32;
typedef unsigned long long u64;
typedef unsigned short u16;

#define NROWS 32768   // 8 * 4096
#define DDIM 1024
#define SLEN 4096
#define NBATCH 8
#define CHUNK 64      // scan chunk length
#define NCHUNK (SLEN / CHUNK)          // 64 chunks per batch
#define TOTCHUNK (NBATCH * NCHUNK)     // 512
#define STEP_STRIDE 36                 // floats per (b,s) step record: [g u64][pad][w16][bt16]

__device__ __forceinline__ u16 f2bf(float f) {
  u32 u = __float_as_uint(f);
  u32 r = (u + 0x7FFFu + ((u >> 16) & 1u)) >> 16;
  return (u16)r;
}
__device__ __forceinline__ float bf2f(u16 h) { return __uint_as_float(((u32)h) << 16); }
__device__ __forceinline__ float sigmoidf_(float v) { return 1.0f / (1.0f + expf(-v)); }

typedef __attribute__((address_space(1))) void gvoid_t;
typedef __attribute__((address_space(3))) void svoid_t;
__device__ __forceinline__ void gload_lds16(const void* g, void* l) {
  __builtin_amdgcn_global_load_lds((gvoid_t*)g, (svoid_t*)l, 16, 0, 0);
}

// ---------------------------------------------------------------- K0: fp32 -> bf16
__global__ __launch_bounds__(256) void k_cvt_bf16(const float* __restrict__ src,
                                                  u16* __restrict__ dst, int n8) {
  int i = blockIdx.x * 256 + threadIdx.x;
  if (i >= n8) return;
  const float4* s4 = (const float4*)src;
  float4 a = s4[2 * i], b = s4[2 * i + 1];
  u32 w0 = (u32)f2bf(a.x) | ((u32)f2bf(a.y) << 16);
  u32 w1 = (u32)f2bf(a.z) | ((u32)f2bf(a.w) << 16);
  u32 w2 = (u32)f2bf(b.x) | ((u32)f2bf(b.y) << 16);
  u32 w3 = (u32)f2bf(b.z) | ((u32)f2bf(b.w) << 16);
  ((uint4*)dst)[i] = make_uint4(w0, w1, w2, w3);
}

// ------------------------------------------- K1: fp64 perm logits + sinkhorn + argmax
// Out: Fbuf[row*2+0] = side-R pack (block r byte r, col j bits 2j), [row*2+1] = side-L.
__global__ __launch_bounds__(256) void k_permlogits(const float* __restrict__ x,
                                                    const float* __restrict__ WpR,
                                                    const float* __restrict__ WpL,
                                                    u32* __restrict__ Fbuf) {
  __shared__ float xs[32 * 36];
  __shared__ float ws[128 * 36];
  __shared__ double Ld[32 * 128];
  __shared__ unsigned char Ftmp[32 * 8];
  const int t = threadIdx.x;
  const int row0 = blockIdx.x * 32;
  const int cg = t & 31, rg = t >> 5;   // cols: cg + 32*ci ; rows: rg*4 + ri
  double acc[4][4];
#pragma unroll
  for (int a = 0; a < 4; a++)
#pragma unroll
    for (int b = 0; b < 4; b++) acc[a][b] = 0.0;

  for (int k0 = 0; k0 < DDIM; k0 += 32) {
    __syncthreads();
    for (int idx = t; idx < 32 * 32; idx += 256) {
      int r = idx >> 5, k = idx & 31;
      xs[r * 36 + k] = x[(size_t)(row0 + r) * DDIM + k0 + k];
    }
    for (int idx = t; idx < 128 * 32; idx += 256) {
      int c = idx >> 5, k = idx & 31;
      float v = (c < 64) ? WpR[c * DDIM + k0 + k] : WpL[(c - 64) * DDIM + k0 + k];
      ws[c * 36 + k] = v;
    }
    __syncthreads();
#pragma unroll
    for (int kk = 0; kk < 32; kk += 4) {
      float4 xv[4], wv[4];
#pragma unroll
      for (int ri = 0; ri < 4; ri++) xv[ri] = *(const float4*)&xs[(rg * 4 + ri) * 36 + kk];
#pragma unroll
      for (int ci = 0; ci < 4; ci++) wv[ci] = *(const float4*)&ws[(cg + 32 * ci) * 36 + kk];
#pragma unroll
      for (int ri = 0; ri < 4; ri++)
#pragma unroll
        for (int ci = 0; ci < 4; ci++) {
          acc[ri][ci] += (double)xv[ri].x * (double)wv[ci].x
                       + (double)xv[ri].y * (double)wv[ci].y
                       + (double)xv[ri].z * (double)wv[ci].z
                       + (double)xv[ri].w * (double)wv[ci].w;
        }
    }
  }
  __syncthreads();
#pragma unroll
  for (int ri = 0; ri < 4; ri++)
#pragma unroll
    for (int ci = 0; ci < 4; ci++)
      Ld[(rg * 4 + ri) * 128 + (cg + 32 * ci)] = acc[ri][ci] * 2.0;  // / TAU
  __syncthreads();
  {
    const int row = t >> 3, blk = t & 7;   // blk 0..3 = side R block, 4..7 = side L
    double a[16];
#pragma unroll
    for (int e = 0; e < 16; e++) a[e] = Ld[row * 128 + blk * 16 + e];
    for (int it = 0; it < 5; it++) {
#pragma unroll
      for (int i = 0; i < 4; i++) {   // row lse (axis -1)
        double m = fmax(fmax(a[i * 4], a[i * 4 + 1]), fmax(a[i * 4 + 2], a[i * 4 + 3]));
        double s = exp(a[i * 4] - m) + exp(a[i * 4 + 1] - m) + exp(a[i * 4 + 2] - m) + exp(a[i * 4 + 3] - m);
        double l = m + log(s);
        a[i * 4] -= l; a[i * 4 + 1] -= l; a[i * 4 + 2] -= l; a[i * 4 + 3] -= l;
      }
#pragma unroll
      for (int j = 0; j < 4; j++) {   // col lse (axis -2)
        double m = fmax(fmax(a[j], a[4 + j]), fmax(a[8 + j], a[12 + j]));
        double s = exp(a[j] - m) + exp(a[4 + j] - m) + exp(a[8 + j] - m) + exp(a[12 + j] - m);
        double l = m + log(s);
        a[j] -= l; a[4 + j] -= l; a[8 + j] -= l; a[12 + j] -= l;
      }
    }
    unsigned char pk = 0;
#pragma unroll
    for (int j = 0; j < 4; j++) {   // argmax over i (first max wins, like np.argmax)
      int best = 0; double bv = a[j];
      if (a[4 + j] > bv)  { bv = a[4 + j];  best = 1; }
      if (a[8 + j] > bv)  { bv = a[8 + j];  best = 2; }
      if (a[12 + j] > bv) { bv = a[12 + j]; best = 3; }
      pk |= (unsigned char)(best << (2 * j));
    }
    Ftmp[row * 8 + blk] = pk;
  }
  __syncthreads();
  if (t < 32) {
    u32 lo = (u32)Ftmp[t * 8 + 0] | ((u32)Ftmp[t * 8 + 1] << 8) |
             ((u32)Ftmp[t * 8 + 2] << 16) | ((u32)Ftmp[t * 8 + 3] << 24);
    u32 hi = (u32)Ftmp[t * 8 + 4] | ((u32)Ftmp[t * 8 + 5] << 8) |
             ((u32)Ftmp[t * 8 + 6] << 16) | ((u32)Ftmp[t * 8 + 7] << 24);
    Fbuf[(row0 + t) * 2] = lo;
    Fbuf[(row0 + t) * 2 + 1] = hi;
  }
}

// ------------------------- K2: fp32 diag/alpha/B projections -> proj[row*48]: dR16,dL16,bt16
__global__ __launch_bounds__(256) void k_proj(const float* __restrict__ x,
                                              const float* __restrict__ WdR, const float* __restrict__ WaR,
                                              const float* __restrict__ WdL, const float* __restrict__ WaL,
                                              const float* __restrict__ WB, const float* __restrict__ mask,
                                              float* __restrict__ proj) {
  __shared__ float xs[64 * 36];
  __shared__ float ws[80 * 36];
  __shared__ float ob[64 * 81];
  const int t = threadIdx.x;
  const int row0 = blockIdx.x * 64;
  const int cg = t & 15, rg = t >> 4;  // cols: cg*5 + ci (5), rows: rg*4 + ri (4)
  float acc[4][5] = {};
  for (int k0 = 0; k0 < DDIM; k0 += 32) {
    __syncthreads();
    for (int idx = t; idx < 64 * 32; idx += 256) {
      int r = idx >> 5, k = idx & 31;
      xs[r * 36 + k] = x[(size_t)(row0 + r) * DDIM + k0 + k];
    }
    for (int idx = t; idx < 80 * 32; idx += 256) {
      int c = idx >> 5, k = idx & 31;
      const float* W = (c < 16) ? WdR + c * DDIM
                    : (c < 32) ? WaR + (c - 16) * DDIM
                    : (c < 48) ? WdL + (c - 32) * DDIM
                    : (c < 64) ? WaL + (c - 48) * DDIM
                               : WB + (c - 64) * DDIM;
      ws[c * 36 + k] = W[k0 + k];
    }
    __syncthreads();
#pragma unroll
    for (int kk = 0; kk < 32; kk += 4) {
      float4 xv[4], wv[5];
#pragma unroll
      for (int ri = 0; ri < 4; ri++) xv[ri] = *(const float4*)&xs[(rg * 4 + ri) * 36 + kk];
#pragma unroll
      for (int ci = 0; ci < 5; ci++) wv[ci] = *(const float4*)&ws[(cg * 5 + ci) * 36 + kk];
#pragma unroll
      for (int ri = 0; ri < 4; ri++)
#pragma unroll
        for (int ci = 0; ci < 5; ci++) {
          acc[ri][ci] += xv[ri].x * wv[ci].x + xv[ri].y * wv[ci].y
                       + xv[ri].z * wv[ci].z + xv[ri].w * wv[ci].w;
        }
    }
  }
  __syncthreads();
#pragma unroll
  for (int ri = 0; ri < 4; ri++)
#pragma unroll
    for (int ci = 0; ci < 5; ci++)
      ob[(rg * 4 + ri) * 81 + cg * 5 + ci] = acc[ri][ci];
  __syncthreads();
  {
    const int row = t >> 2, ng = t & 3;
    float mv = mask[row0 + row];
    size_t base = (size_t)(row0 + row) * 48;
#pragma unroll
    for (int nn = 0; nn < 4; nn++) {
      int n = ng * 4 + nn;
      float dRv = sigmoidf_(ob[row * 81 + 16 + n]) * tanhf(ob[row * 81 + n]);
      float dLv = sigmoidf_(ob[row * 81 + 48 + n]) * tanhf(ob[row * 81 + 32 + n]);
      float btv = ob[row * 81 + 64 + n] * mv;
      proj[base + n] = dRv;
      proj[base + 16 + n] = dLv;
      proj[base + 32 + n] = btv;
    }
  }
}

// ----------------- K3: build per-step functional operator: g (packed u64), w[16], bt[16]
__global__ __launch_bounds__(256) void k_combine(const u32* __restrict__ Fbuf,
                                                 const float* __restrict__ proj,
                                                 float* __restrict__ step) {
  __shared__ float lds[256 * 33];
  const int t = threadIdx.x;
  const int row = blockIdx.x * 256 + t;
  float* reg = &lds[t * 33];
  const float* p = proj + (size_t)row * 48;
#pragma unroll
  for (int n = 0; n < 16; n++) reg[n] = p[n];          // dR
#pragma unroll
  for (int n = 0; n < 16; n++) reg[16 + n] = p[16 + n]; // dL
  u32 FRp = Fbuf[row * 2], FLp = Fbuf[row * 2 + 1];
  u64 gp = 0;
  float w[16];
#pragma unroll
  for (int j = 0; j < 16; j++) {
    int r = j >> 2, c = j & 3;
    int i  = (int)((FRp >> (r * 8 + c * 2)) & 3u);  // stage-R dest row within block r
    int k1 = 4 * r + i;
    float wR = reg[k1];
    // shuffle (transpose involution): k2 = 4*i + r
    int i2 = (int)((FLp >> (i * 8 + r * 2)) & 3u);  // stage-L: block i, col r
    int k3 = 4 * i + i2;
    float wL = reg[16 + k3];
    gp |= ((u64)(u32)k3) << (4 * j);
    w[j] = wR * wL;
  }
  float* sp = step + (size_t)row * STEP_STRIDE;
  *(u64*)sp = gp;
#pragma unroll
  for (int j = 0; j < 16; j++) sp[4 + j] = w[j];
#pragma unroll
  for (int n = 0; n < 16; n++) sp[20 + n] = p[32 + n]; // bt (mask already applied)
}

#define LD16F(dst, ptr)                                     \
  {                                                         \
    float4 _a = *(const float4*)((ptr));                    \
    float4 _b = *(const float4*)((ptr) + 4);                \
    float4 _c = *(const float4*)((ptr) + 8);                \
    float4 _d = *(const float4*)((ptr) + 12);               \
    dst[0] = _a.x; dst[1] = _a.y; dst[2] = _a.z; dst[3] = _a.w;   \
    dst[4] = _b.x; dst[5] = _b.y; dst[6] = _b.z; dst[7] = _b.w;   \
    dst[8] = _c.x; dst[9] = _c.y; dst[10] = _c.z; dst[11] = _c.w; \
    dst[12] = _d.x; dst[13] = _d.y; dst[14] = _d.z; dst[15] = _d.w; }

// ------------------------------ K4: per-chunk composition of 64 step operators
__global__ __launch_bounds__(64) void k_compose(const float* __restrict__ step,
                                                float* __restrict__ comp) {
  __shared__ float lds[64 * 34];
  const int t = threadIdx.x;
  const int chunk = blockIdx.x * 64 + t;
  float* Wl = &lds[t * 34];
  float* Tm = Wl + 17;
  const int b = chunk >> 6, c = chunk & 63;
  const size_t base = ((size_t)b * SLEN + (size_t)c * CHUNK) * STEP_STRIDE;
  u64 G = 0xFEDCBA9876543210ull;  // identity map
  float Wc[16], Bc[16];
#pragma unroll
  for (int k = 0; k < 16; k++) { Wc[k] = 1.0f; Bc[k] = 0.0f; }
  for (int s = 0; s < CHUNK; s++) {
    const float* sp = step + base + (size_t)s * STEP_STRIDE;
    u64 gp = *(const u64*)sp;
    float w[16], bt[16];
    LD16F(w, sp + 4);
    LD16F(bt, sp + 20);
#pragma unroll
    for (int n = 0; n < 16; n++) Wl[n] = w[n];
    u64 nG = 0;
#pragma unroll
    for (int k = 0; k < 16; k++) {
      int Gk = (int)((G >> (4 * k)) & 15ull);
      Wc[k] *= Wl[Gk];
      nG |= ((gp >> (4 * Gk)) & 15ull) << (4 * k);
    }
#pragma unroll
    for (int i = 0; i < 16; i++) Tm[i] = bt[i];
#pragma unroll
    for (int j = 0; j < 16; j++) {
      int gj = (int)((gp >> (4 * j)) & 15ull);
      Tm[gj] += w[j] * Bc[j];
    }
#pragma unroll
    for (int i = 0; i < 16; i++) Bc[i] = Tm[i];
    G = nG;
  }
  float* cp = comp + (size_t)chunk * STEP_STRIDE;
  *(u64*)cp = G;
#pragma unroll
  for (int k = 0; k < 16; k++) cp[4 + k] = Wc[k];
#pragma unroll
  for (int k = 0; k < 16; k++) cp[20 + k] = Bc[k];
}

// ---------------------- K5: sequential scan over chunk composites (per batch) -> h at chunk starts
__global__ __launch_bounds__(64) void k_bscan(const float* __restrict__ comp,
                                              float* __restrict__ hstart) {
  __shared__ float lds[64 * 17];
  const int t = threadIdx.x;
  if (t >= NBATCH) return;
  float* Tm = &lds[t * 17];
  float h[16];
#pragma unroll
  for (int i = 0; i < 16; i++) h[i] = 0.0f;
  for (int c = 0; c < NCHUNK; c++) {
    int chunk = t * NCHUNK + c;
    const float* cp = comp + (size_t)chunk * STEP_STRIDE;
    u64 G = *(const u64*)cp;
    float Wc[16], Bc[16];
    LD16F(Wc, cp + 4);
    LD16F(Bc, cp + 20);
    float* hp = hstart + (size_t)chunk * 16;
#pragma unroll
    for (int i = 0; i < 16; i++) hp[i] = h[i];
#pragma unroll
    for (int i = 0; i < 16; i++) Tm[i] = Bc[i];
#pragma unroll
    for (int k = 0; k < 16; k++) {
      int Gk = (int)((G >> (4 * k)) & 15ull);
      Tm[Gk] += Wc[k] * h[k];
    }
#pragma unroll
    for (int i = 0; i < 16; i++) h[i] = Tm[i];
  }
}

// ------------------------------ K6: re-apply steps within each chunk, emit hs[row*16]
__global__ __launch_bounds__(64) void k_apply(const float* __restrict__ step,
                                              const float* __restrict__ hstart,
                                              float* __restrict__ hs) {
  __shared__ float lds[64 * 17];
  const int t = threadIdx.x;
  const int chunk = blockIdx.x * 64 + t;
  float* Tm = &lds[t * 17];
  const int b = chunk >> 6, c = chunk & 63;
  const size_t srow = (size_t)b * SLEN + (size_t)c * CHUNK;
  float h[16];
  {
    const float* hp = hstart + (size_t)chunk * 16;
    LD16F(h, hp);
  }
  for (int s = 0; s < CHUNK; s++) {
    const float* sp = step + (srow + s) * STEP_STRIDE;
    u64 gp = *(const u64*)sp;
    float w[16], bt[16];
    LD16F(w, sp + 4);
    LD16F(bt, sp + 20);
#pragma unroll
    for (int i = 0; i < 16; i++) Tm[i] = bt[i];
#pragma unroll
    for (int j = 0; j < 16; j++) {
      int gj = (int)((gp >> (4 * j)) & 15ull);
      Tm[gj] += w[j] * h[j];
    }
#pragma unroll
    for (int i = 0; i < 16; i++) h[i] = Tm[i];
    float* op = hs + (srow + s) * 16;
    float4 v0 = make_float4(h[0], h[1], h[2], h[3]);
    float4 v1 = make_float4(h[4], h[5], h[6], h[7]);
    float4 v2 = make_float4(h[8], h[9], h[10], h[11]);
    float4 v3 = make_float4(h[12], h[13], h[14], h[15]);
    *(float4*)(op) = v0; *(float4*)(op + 4) = v1;
    *(float4*)(op + 8) = v2; *(float4*)(op + 12) = v3;
  }
}

// ------------------------------ K7: bf16 MFMA GEMM gate = sigmoid(x @ Wgate^T), store bf16
typedef __attribute__((ext_vector_type(8))) short bfrag;
typedef __attribute__((ext_vector_type(4))) float ffrag;

__global__ __launch_bounds__(256) void k_gemm(const u16* __restrict__ A,
                                              const u16* __restrict__ B,
                                              u16* __restrict__ Gout) {
  __shared__ u16 As[128 * 32];
  __shared__ u16 Bs[128 * 32];
  const int t = threadIdx.x;
  const int wave = t >> 6, lane = t & 63;
  const int wm = (wave & 1) << 6, wn = (wave >> 1) << 6;
  const int r = lane & 15, q = lane >> 4;
  const int row0 = blockIdx.x << 7, col0 = blockIdx.y << 7;
  ffrag acc[4][4];
#pragma unroll
  for (int mi = 0; mi < 4; mi++)
#pragma unroll
    for (int ni = 0; ni < 4; ni++)
#pragma unroll
      for (int e = 0; e < 4; e++) acc[mi][ni][e] = 0.0f;

  const int segr = t >> 2;             // row within half-tile
  const int segk = (t & 3) << 3;       // k element offset {0,8,16,24}
  const u16* gA0 = A + (size_t)(row0 + segr) * DDIM + segk;
  const u16* gA1 = A + (size_t)(row0 + 64 + segr) * DDIM + segk;
  const u16* gB0 = B + (size_t)(col0 + segr) * DDIM + segk;
  const u16* gB1 = B + (size_t)(col0 + 64 + segr) * DDIM + segk;

  for (int k0 = 0; k0 < DDIM; k0 += 32) {
    gload_lds16(gA0 + k0, &As[(0 * 256 + t) * 8]);
    gload_lds16(gA1 + k0, &As[(1 * 256 + t) * 8]);
    gload_lds16(gB0 + k0, &Bs[(0 * 256 + t) * 8]);
    gload_lds16(gB1 + k0, &Bs[(1 * 256 + t) * 8]);
    __syncthreads();
    bfrag af[4], bf[4];
#pragma unroll
    for (int mi = 0; mi < 4; mi++) af[mi] = *(const bfrag*)&As[(wm + mi * 16 + r) * 32 + q * 8];
#pragma unroll
    for (int ni = 0; ni < 4; ni++) bf[ni] = *(const bfrag*)&Bs[(wn + ni * 16 + r) * 32 + q * 8];
#pragma unroll
    for (int mi = 0; mi < 4; mi++)
#pragma unroll
      for (int ni = 0; ni < 4; ni++)
        acc[mi][ni] = __builtin_amdgcn_mfma_f32_16x16x32_bf16(af[mi], bf[ni], acc[mi][ni], 0, 0, 0);
    __syncthreads();
  }
#pragma unroll
  for (int mi = 0; mi < 4; mi++)
#pragma unroll
    for (int ni = 0; ni < 4; ni++)
#pragma unroll
      for (int e = 0; e < 4; e++) {
        int rr = row0 + wm + mi * 16 + q * 4 + e;
        int cc = col0 + wn + ni * 16 + r;
        float v = acc[mi][ni][e];
        Gout[(size_t)rr * DDIM + cc] = f2bf(1.0f / (1.0f + __expf(-v)));
      }
}

// ------------------------------ K8: y = gate * (hs @ W_C^T); RMSNorm; write out
__global__ __launch_bounds__(1024) void k_final(const float* __restrict__ hs,
                                                const u16* __restrict__ gate,
                                                const float* __restrict__ WC,
                                                const float* __restrict__ norm_w,
                                                float* __restrict__ out,
                                                int rows_per_block) {
  __shared__ float red[2][16];
  const int t = threadIdx.x;     // t == d (0..1023)
  const int wv = t >> 6;
  float wct[16];
#pragma unroll
  for (int n4 = 0; n4 < 4; n4++) {
    float4 v = *(const float4*)&WC[t * 16 + n4 * 4];
    wct[n4 * 4 + 0] = v.x; wct[n4 * 4 + 1] = v.y;
    wct[n4 * 4 + 2] = v.z; wct[n4 * 4 + 3] = v.w;
  }
  const float nw = norm_w[t];
  const int row0 = blockIdx.x * rows_per_block;
  for (int rr = 0; rr < rows_per_block; rr++) {
    const int row = row0 + rr;
    const float* hp = hs + (size_t)row * 16;
    float4 h0 = *(const float4*)hp;
    float4 h1 = *(const float4*)(hp + 4);
    float4 h2 = *(const float4*)(hp + 8);
    float4 h3 = *(const float4*)(hp + 12);
    float z = wct[0] * h0.x + wct[1] * h0.y + wct[2] * h0.z + wct[3] * h0.w
            + wct[4] * h1.x + wct[5] * h1.y + wct[6] * h1.z + wct[7] * h1.w
            + wct[8] * h2.x + wct[9] * h2.y + wct[10] * h2.z + wct[11] * h2.w
            + wct[12] * h3.x + wct[13] * h3.y + wct[14] * h3.z + wct[15] * h3.w;
    float g = bf2f(gate[(size_t)row * DDIM + t]);
    float y = g * z;
    float p = y * y;
#pragma unroll
    for (int o = 32; o > 0; o >>= 1) p += __shfl_down(p, o, 64);
    const int pb = rr & 1;
    if ((t & 63) == 0) red[pb][wv] = p;
    __syncthreads();
    float tot = 0.0f;
#pragma unroll
    for (int i2 = 0; i2 < 16; i2++) tot += red[pb][i2];
    float inv = 1.0f / sqrtf(tot * (1.0f / 1024.0f) + 1e-6f);
    out[(size_t)row * DDIM + t] = y * inv * nw;
  }
}

// ---------------------------------------------------------------- launcher
extern "C" void kernel_launch(void* const* d_in, const int* in_sizes, int n_in,
                              void* d_out, int out_size, void* d_ws, size_t ws_size,
                              hipStream_t stream) {
  const float* x     = (const float*)d_in[0];
  const float* mask  = (const float*)d_in[1];
  const float* WpR   = (const float*)d_in[2];
  const float* WdR   = (const float*)d_in[3];
  const float* WaR   = (const float*)d_in[4];
  const float* WpL   = (const float*)d_in[5];
  const float* WdL   = (const float*)d_in[6];
  const float* WaL   = (const float*)d_in[7];
  const float* WB    = (const float*)d_in[8];
  const float* WC    = (const float*)d_in[9];
  const float* Wg    = (const float*)d_in[10];
  const float* normw = (const float*)d_in[11];
  // shuffle_perm (d_in[12]) is the deterministic stride transpose; hardcoded in K3.
  float* out = (float*)d_out;
  char* ws = (char*)d_ws;

  // workspace layout (bytes). F/proj/step/comp/hstart are aliased into the gate
  // region: they are fully consumed (K3..K6) before K7 writes gate. Total: ~132 MB.
  u16*   xb   = (u16*)(ws + 0);            // 67108864  x as bf16
  u16*   wgb  = (u16*)(ws + 67108864);     //  2097152  W_gate as bf16
  float* hs   = (float*)(ws + 69206016);   //  2097152  scan outputs
  u16*   gate = (u16*)(ws + 71303168);     // 67108864  sigmoid(x Wg^T) as bf16
  u32*   F    = (u32*)(ws + 71303168);     //   262144  argmax packs (aliased)
  float* proj = (float*)(ws + 71565312);   //  6291456  dR/dL/bt        (aliased)
  float* step = (float*)(ws + 77856768);   //  4718592  step operators  (aliased)
  float* comp = (float*)(ws + 82575360);   //    73728  chunk composites(aliased)
  float* hst  = (float*)(ws + 82649088);   //    32768  chunk-start h   (aliased)

  k_cvt_bf16<<<16384, 256, 0, stream>>>(x, xb, 4194304);
  k_cvt_bf16<<<512, 256, 0, stream>>>(Wg, wgb, 131072);
  k_permlogits<<<1024, 256, 0, stream>>>(x, WpR, WpL, F);
  k_proj<<<512, 256, 0, stream>>>(x, WdR, WaR, WdL, WaL, WB, mask, proj);
  k_combine<<<128, 256, 0, stream>>>(F, proj, step);
  k_compose<<<8, 64, 0, stream>>>(step, comp);
  k_bscan<<<1, 64, 0, stream>>>(comp, hst);
  k_apply<<<8, 64, 0, stream>>>(step, hst, hs);
  k_gemm<<<dim3(256, 8), 256, 0, stream>>>(xb, wgb, gate);
  k_final<<<256, 1024, 0, stream>>>(hs, gate, WC, normw, out, 128);
}

// Round 2
// 1512.984 us; speedup vs baseline: 1.2239x; 1.2239x over previous
//
#include <hip/hip_runtime.h>
#include <hip/hip_bf16.h>
#include <math.h>
#include <stdint.h>

typedef unsigned int u32;
typedef unsigned long long u64;
typedef unsigned short u16;

#define NROWS 32768   // 8 * 4096
#define DDIM 1024
#define SLEN 4096
#define NBATCH 8
#define CHUNK 64      // scan chunk length
#define NCHUNK (SLEN / CHUNK)          // 64 chunks per batch
#define TOTCHUNK (NBATCH * NCHUNK)     // 512
#define STEP_STRIDE 36                 // floats per (b,s) step record: [g u64][pad][w16][bt16]

__device__ __forceinline__ u16 f2bf(float f) {
  u32 u = __float_as_uint(f);
  u32 r = (u + 0x7FFFu + ((u >> 16) & 1u)) >> 16;
  return (u16)r;
}
__device__ __forceinline__ float bf2f(u16 h) { return __uint_as_float(((u32)h) << 16); }
__device__ __forceinline__ float sigmoidf_(float v) { return 1.0f / (1.0f + expf(-v)); }

typedef __attribute__((address_space(1))) void gvoid_t;
typedef __attribute__((address_space(3))) void svoid_t;
__device__ __forceinline__ void gload_lds16(const void* g, void* l) {
  __builtin_amdgcn_global_load_lds((gvoid_t*)g, (svoid_t*)l, 16, 0, 0);
}

// ---------------------------------------------------------------- K0: fp32 -> bf16
__global__ __launch_bounds__(256) void k_cvt_bf16(const float* __restrict__ src,
                                                  u16* __restrict__ dst, int n8) {
  int i = blockIdx.x * 256 + threadIdx.x;
  if (i >= n8) return;
  const float4* s4 = (const float4*)src;
  float4 a = s4[2 * i], b = s4[2 * i + 1];
  u32 w0 = (u32)f2bf(a.x) | ((u32)f2bf(a.y) << 16);
  u32 w1 = (u32)f2bf(a.z) | ((u32)f2bf(a.w) << 16);
  u32 w2 = (u32)f2bf(b.x) | ((u32)f2bf(b.y) << 16);
  u32 w3 = (u32)f2bf(b.z) | ((u32)f2bf(b.w) << 16);
  ((uint4*)dst)[i] = make_uint4(w0, w1, w2, w3);
}

// ------------------------------------------- K1: fp64 perm logits + sinkhorn + argmax
// Each thread owns one (row, blk) 4x4 sinkhorn unit: 16 fp64 dot-products in-register.
// W tile in LDS layout [k][blk*20 + e] (skew 20 -> 4 conflict-free ds_read_b128/thread/k).
// Summation order over k is bit-identical to the previous (verified-passing) version.
#define WS_STRIDE 160
__global__ __launch_bounds__(256) void k_permlogits(const float* __restrict__ x,
                                                    const float* __restrict__ WpR,
                                                    const float* __restrict__ WpL,
                                                    u32* __restrict__ Fbuf) {
  __shared__ float xs[32 * 36];
  __shared__ float ws[32 * WS_STRIDE];
  __shared__ unsigned char Ftmp[32 * 8];
  const int t = threadIdx.x;
  const int row0 = blockIdx.x * 32;
  const int row = t >> 3, blk = t & 7;   // blk 0..3 = R-side blocks, 4..7 = L-side
  double acc[16];
#pragma unroll
  for (int e = 0; e < 16; e++) acc[e] = 0.0;

  for (int k0 = 0; k0 < DDIM; k0 += 32) {
    __syncthreads();
    {
      int r = t >> 3, kc = (t & 7) << 2;
      float4 v = *(const float4*)&x[(size_t)(row0 + r) * DDIM + k0 + kc];
      xs[r * 36 + kc + 0] = v.x; xs[r * 36 + kc + 1] = v.y;
      xs[r * 36 + kc + 2] = v.z; xs[r * 36 + kc + 3] = v.w;
    }
#pragma unroll
    for (int it = 0; it < 4; it++) {
      int idx = it * 256 + t;
      int c = idx >> 3, kc = (idx & 7) << 2;
      const float* W = (c < 64) ? (WpR + (size_t)c * DDIM) : (WpL + (size_t)(c - 64) * DDIM);
      float4 v = *(const float4*)&W[k0 + kc];
      int base = ((c >> 4) * 20) + (c & 15);
      ws[(kc + 0) * WS_STRIDE + base] = v.x;
      ws[(kc + 1) * WS_STRIDE + base] = v.y;
      ws[(kc + 2) * WS_STRIDE + base] = v.z;
      ws[(kc + 3) * WS_STRIDE + base] = v.w;
    }
    __syncthreads();
#pragma unroll 4
    for (int k = 0; k < 32; k++) {
      double xd = (double)xs[row * 36 + k];
      const float* wp = &ws[k * WS_STRIDE + blk * 20];
      float4 w0 = *(const float4*)(wp);
      float4 w1 = *(const float4*)(wp + 4);
      float4 w2 = *(const float4*)(wp + 8);
      float4 w3 = *(const float4*)(wp + 12);
      acc[0]  += xd * (double)w0.x;  acc[1]  += xd * (double)w0.y;
      acc[2]  += xd * (double)w0.z;  acc[3]  += xd * (double)w0.w;
      acc[4]  += xd * (double)w1.x;  acc[5]  += xd * (double)w1.y;
      acc[6]  += xd * (double)w1.z;  acc[7]  += xd * (double)w1.w;
      acc[8]  += xd * (double)w2.x;  acc[9]  += xd * (double)w2.y;
      acc[10] += xd * (double)w2.z;  acc[11] += xd * (double)w2.w;
      acc[12] += xd * (double)w3.x;  acc[13] += xd * (double)w3.y;
      acc[14] += xd * (double)w3.z;  acc[15] += xd * (double)w3.w;
    }
  }
  // ---- Sinkhorn (fp64, in-register; math identical to previous version) ----
  {
    double a[16];
#pragma unroll
    for (int e = 0; e < 16; e++) a[e] = acc[e] * 2.0;  // / TAU
    for (int it = 0; it < 5; it++) {
#pragma unroll
      for (int i = 0; i < 4; i++) {   // row lse (axis -1)
        double m = fmax(fmax(a[i * 4], a[i * 4 + 1]), fmax(a[i * 4 + 2], a[i * 4 + 3]));
        double s = exp(a[i * 4] - m) + exp(a[i * 4 + 1] - m) + exp(a[i * 4 + 2] - m) + exp(a[i * 4 + 3] - m);
        double l = m + log(s);
        a[i * 4] -= l; a[i * 4 + 1] -= l; a[i * 4 + 2] -= l; a[i * 4 + 3] -= l;
      }
#pragma unroll
      for (int j = 0; j < 4; j++) {   // col lse (axis -2)
        double m = fmax(fmax(a[j], a[4 + j]), fmax(a[8 + j], a[12 + j]));
        double s = exp(a[j] - m) + exp(a[4 + j] - m) + exp(a[8 + j] - m) + exp(a[12 + j] - m);
        double l = m + log(s);
        a[j] -= l; a[4 + j] -= l; a[8 + j] -= l; a[12 + j] -= l;
      }
    }
    unsigned char pk = 0;
#pragma unroll
    for (int j = 0; j < 4; j++) {   // argmax over i (first max wins, like np.argmax)
      int best = 0; double bv = a[j];
      if (a[4 + j] > bv)  { bv = a[4 + j];  best = 1; }
      if (a[8 + j] > bv)  { bv = a[8 + j];  best = 2; }
      if (a[12 + j] > bv) { bv = a[12 + j]; best = 3; }
      pk |= (unsigned char)(best << (2 * j));
    }
    Ftmp[row * 8 + blk] = pk;
  }
  __syncthreads();
  if (t < 32) {
    u32 lo = (u32)Ftmp[t * 8 + 0] | ((u32)Ftmp[t * 8 + 1] << 8) |
             ((u32)Ftmp[t * 8 + 2] << 16) | ((u32)Ftmp[t * 8 + 3] << 24);
    u32 hi = (u32)Ftmp[t * 8 + 4] | ((u32)Ftmp[t * 8 + 5] << 8) |
             ((u32)Ftmp[t * 8 + 6] << 16) | ((u32)Ftmp[t * 8 + 7] << 24);
    Fbuf[(row0 + t) * 2] = lo;
    Fbuf[(row0 + t) * 2 + 1] = hi;
  }
}

// ------------------------- K2: fp32 diag/alpha/B projections -> proj[row*48]: dR16,dL16,bt16
__global__ __launch_bounds__(256) void k_proj(const float* __restrict__ x,
                                              const float* __restrict__ WdR, const float* __restrict__ WaR,
                                              const float* __restrict__ WdL, const float* __restrict__ WaL,
                                              const float* __restrict__ WB, const float* __restrict__ mask,
                                              float* __restrict__ proj) {
  __shared__ float xs[64 * 36];
  __shared__ float ws[80 * 36];
  __shared__ float ob[64 * 81];
  const int t = threadIdx.x;
  const int row0 = blockIdx.x * 64;
  const int cg = t & 15, rg = t >> 4;  // cols: cg*5 + ci (5), rows: rg*4 + ri (4)
  float acc[4][5] = {};
  for (int k0 = 0; k0 < DDIM; k0 += 32) {
    __syncthreads();
    for (int idx = t; idx < 64 * 32; idx += 256) {
      int r = idx >> 5, k = idx & 31;
      xs[r * 36 + k] = x[(size_t)(row0 + r) * DDIM + k0 + k];
    }
    for (int idx = t; idx < 80 * 32; idx += 256) {
      int c = idx >> 5, k = idx & 31;
      const float* W = (c < 16) ? WdR + c * DDIM
                    : (c < 32) ? WaR + (c - 16) * DDIM
                    : (c < 48) ? WdL + (c - 32) * DDIM
                    : (c < 64) ? WaL + (c - 48) * DDIM
                               : WB + (c - 64) * DDIM;
      ws[c * 36 + k] = W[k0 + k];
    }
    __syncthreads();
#pragma unroll
    for (int kk = 0; kk < 32; kk += 4) {
      float4 xv[4], wv[5];
#pragma unroll
      for (int ri = 0; ri < 4; ri++) xv[ri] = *(const float4*)&xs[(rg * 4 + ri) * 36 + kk];
#pragma unroll
      for (int ci = 0; ci < 5; ci++) wv[ci] = *(const float4*)&ws[(cg * 5 + ci) * 36 + kk];
#pragma unroll
      for (int ri = 0; ri < 4; ri++)
#pragma unroll
        for (int ci = 0; ci < 5; ci++) {
          acc[ri][ci] += xv[ri].x * wv[ci].x + xv[ri].y * wv[ci].y
                       + xv[ri].z * wv[ci].z + xv[ri].w * wv[ci].w;
        }
    }
  }
  __syncthreads();
#pragma unroll
  for (int ri = 0; ri < 4; ri++)
#pragma unroll
    for (int ci = 0; ci < 5; ci++)
      ob[(rg * 4 + ri) * 81 + cg * 5 + ci] = acc[ri][ci];
  __syncthreads();
  {
    const int row = t >> 2, ng = t & 3;
    float mv = mask[row0 + row];
    size_t base = (size_t)(row0 + row) * 48;
#pragma unroll
    for (int nn = 0; nn < 4; nn++) {
      int n = ng * 4 + nn;
      float dRv = sigmoidf_(ob[row * 81 + 16 + n]) * tanhf(ob[row * 81 + n]);
      float dLv = sigmoidf_(ob[row * 81 + 48 + n]) * tanhf(ob[row * 81 + 32 + n]);
      float btv = ob[row * 81 + 64 + n] * mv;
      proj[base + n] = dRv;
      proj[base + 16 + n] = dLv;
      proj[base + 32 + n] = btv;
    }
  }
}

// ----------------- K3: build per-step functional operator: g (packed u64), w[16], bt[16]
__global__ __launch_bounds__(256) void k_combine(const u32* __restrict__ Fbuf,
                                                 const float* __restrict__ proj,
                                                 float* __restrict__ step) {
  __shared__ float lds[256 * 33];
  const int t = threadIdx.x;
  const int row = blockIdx.x * 256 + t;
  float* reg = &lds[t * 33];
  const float* p = proj + (size_t)row * 48;
#pragma unroll
  for (int n = 0; n < 16; n++) reg[n] = p[n];          // dR
#pragma unroll
  for (int n = 0; n < 16; n++) reg[16 + n] = p[16 + n]; // dL
  u32 FRp = Fbuf[row * 2], FLp = Fbuf[row * 2 + 1];
  u64 gp = 0;
  float w[16];
#pragma unroll
  for (int j = 0; j < 16; j++) {
    int r = j >> 2, c = j & 3;
    int i  = (int)((FRp >> (r * 8 + c * 2)) & 3u);  // stage-R dest row within block r
    int k1 = 4 * r + i;
    float wR = reg[k1];
    // shuffle (transpose involution): k2 = 4*i + r
    int i2 = (int)((FLp >> (i * 8 + r * 2)) & 3u);  // stage-L: block i, col r
    int k3 = 4 * i + i2;
    float wL = reg[16 + k3];
    gp |= ((u64)(u32)k3) << (4 * j);
    w[j] = wR * wL;
  }
  float* sp = step + (size_t)row * STEP_STRIDE;
  *(u64*)sp = gp;
#pragma unroll
  for (int j = 0; j < 16; j++) sp[4 + j] = w[j];
#pragma unroll
  for (int n = 0; n < 16; n++) sp[20 + n] = p[32 + n]; // bt (mask already applied)
}

#define LD16F(dst, ptr)                                     \
  {                                                         \
    float4 _a = *(const float4*)((ptr));                    \
    float4 _b = *(const float4*)((ptr) + 4);                \
    float4 _c = *(const float4*)((ptr) + 8);                \
    float4 _d = *(const float4*)((ptr) + 12);               \
    dst[0] = _a.x; dst[1] = _a.y; dst[2] = _a.z; dst[3] = _a.w;   \
    dst[4] = _b.x; dst[5] = _b.y; dst[6] = _b.z; dst[7] = _b.w;   \
    dst[8] = _c.x; dst[9] = _c.y; dst[10] = _c.z; dst[11] = _c.w; \
    dst[12] = _d.x; dst[13] = _d.y; dst[14] = _d.z; dst[15] = _d.w; }

// ------------------------------ K4: per-chunk composition of 64 step operators
__global__ __launch_bounds__(64) void k_compose(const float* __restrict__ step,
                                                float* __restrict__ comp) {
  __shared__ float lds[64 * 34];
  const int t = threadIdx.x;
  const int chunk = blockIdx.x * 64 + t;
  float* Wl = &lds[t * 34];
  float* Tm = Wl + 17;
  const int b = chunk >> 6, c = chunk & 63;
  const size_t base = ((size_t)b * SLEN + (size_t)c * CHUNK) * STEP_STRIDE;
  u64 G = 0xFEDCBA9876543210ull;  // identity map
  float Wc[16], Bc[16];
#pragma unroll
  for (int k = 0; k < 16; k++) { Wc[k] = 1.0f; Bc[k] = 0.0f; }
  for (int s = 0; s < CHUNK; s++) {
    const float* sp = step + base + (size_t)s * STEP_STRIDE;
    u64 gp = *(const u64*)sp;
    float w[16], bt[16];
    LD16F(w, sp + 4);
    LD16F(bt, sp + 20);
#pragma unroll
    for (int n = 0; n < 16; n++) Wl[n] = w[n];
    u64 nG = 0;
#pragma unroll
    for (int k = 0; k < 16; k++) {
      int Gk = (int)((G >> (4 * k)) & 15ull);
      Wc[k] *= Wl[Gk];
      nG |= ((gp >> (4 * Gk)) & 15ull) << (4 * k);
    }
#pragma unroll
    for (int i = 0; i < 16; i++) Tm[i] = bt[i];
#pragma unroll
    for (int j = 0; j < 16; j++) {
      int gj = (int)((gp >> (4 * j)) & 15ull);
      Tm[gj] += w[j] * Bc[j];
    }
#pragma unroll
    for (int i = 0; i < 16; i++) Bc[i] = Tm[i];
    G = nG;
  }
  float* cp = comp + (size_t)chunk * STEP_STRIDE;
  *(u64*)cp = G;
#pragma unroll
  for (int k = 0; k < 16; k++) cp[4 + k] = Wc[k];
#pragma unroll
  for (int k = 0; k < 16; k++) cp[20 + k] = Bc[k];
}

// ---------------------- K5: sequential scan over chunk composites (per batch) -> h at chunk starts
__global__ __launch_bounds__(64) void k_bscan(const float* __restrict__ comp,
                                              float* __restrict__ hstart) {
  __shared__ float lds[64 * 17];
  const int t = threadIdx.x;
  if (t >= NBATCH) return;
  float* Tm = &lds[t * 17];
  float h[16];
#pragma unroll
  for (int i = 0; i < 16; i++) h[i] = 0.0f;
  for (int c = 0; c < NCHUNK; c++) {
    int chunk = t * NCHUNK + c;
    const float* cp = comp + (size_t)chunk * STEP_STRIDE;
    u64 G = *(const u64*)cp;
    float Wc[16], Bc[16];
    LD16F(Wc, cp + 4);
    LD16F(Bc, cp + 20);
    float* hp = hstart + (size_t)chunk * 16;
#pragma unroll
    for (int i = 0; i < 16; i++) hp[i] = h[i];
#pragma unroll
    for (int i = 0; i < 16; i++) Tm[i] = Bc[i];
#pragma unroll
    for (int k = 0; k < 16; k++) {
      int Gk = (int)((G >> (4 * k)) & 15ull);
      Tm[Gk] += Wc[k] * h[k];
    }
#pragma unroll
    for (int i = 0; i < 16; i++) h[i] = Tm[i];
  }
}

// ------------------------------ K6: re-apply steps within each chunk, emit hs[row*16]
__global__ __launch_bounds__(64) void k_apply(const float* __restrict__ step,
                                              const float* __restrict__ hstart,
                                              float* __restrict__ hs) {
  __shared__ float lds[64 * 17];
  const int t = threadIdx.x;
  const int chunk = blockIdx.x * 64 + t;
  float* Tm = &lds[t * 17];
  const int b = chunk >> 6, c = chunk & 63;
  const size_t srow = (size_t)b * SLEN + (size_t)c * CHUNK;
  float h[16];
  {
    const float* hp = hstart + (size_t)chunk * 16;
    LD16F(h, hp);
  }
  for (int s = 0; s < CHUNK; s++) {
    const float* sp = step + (srow + s) * STEP_STRIDE;
    u64 gp = *(const u64*)sp;
    float w[16], bt[16];
    LD16F(w, sp + 4);
    LD16F(bt, sp + 20);
#pragma unroll
    for (int i = 0; i < 16; i++) Tm[i] = bt[i];
#pragma unroll
    for (int j = 0; j < 16; j++) {
      int gj = (int)((gp >> (4 * j)) & 15ull);
      Tm[gj] += w[j] * h[j];
    }
#pragma unroll
    for (int i = 0; i < 16; i++) h[i] = Tm[i];
    float* op = hs + (srow + s) * 16;
    float4 v0 = make_float4(h[0], h[1], h[2], h[3]);
    float4 v1 = make_float4(h[4], h[5], h[6], h[7]);
    float4 v2 = make_float4(h[8], h[9], h[10], h[11]);
    float4 v3 = make_float4(h[12], h[13], h[14], h[15]);
    *(float4*)(op) = v0; *(float4*)(op + 4) = v1;
    *(float4*)(op + 8) = v2; *(float4*)(op + 12) = v3;
  }
}

// ------------------------------ K7: bf16 MFMA GEMM gate = sigmoid(x @ Wgate^T), store bf16
typedef __attribute__((ext_vector_type(8))) short bfrag;
typedef __attribute__((ext_vector_type(4))) float ffrag;

__global__ __launch_bounds__(256) void k_gemm(const u16* __restrict__ A,
                                              const u16* __restrict__ B,
                                              u16* __restrict__ Gout) {
  __shared__ u16 As[128 * 32];
  __shared__ u16 Bs[128 * 32];
  const int t = threadIdx.x;
  const int wave = t >> 6, lane = t & 63;
  const int wm = (wave & 1) << 6, wn = (wave >> 1) << 6;
  const int r = lane & 15, q = lane >> 4;
  const int row0 = blockIdx.x << 7, col0 = blockIdx.y << 7;
  ffrag acc[4][4];
#pragma unroll
  for (int mi = 0; mi < 4; mi++)
#pragma unroll
    for (int ni = 0; ni < 4; ni++)
#pragma unroll
      for (int e = 0; e < 4; e++) acc[mi][ni][e] = 0.0f;

  const int segr = t >> 2;             // row within half-tile
  const int segk = (t & 3) << 3;       // k element offset {0,8,16,24}
  const u16* gA0 = A + (size_t)(row0 + segr) * DDIM + segk;
  const u16* gA1 = A + (size_t)(row0 + 64 + segr) * DDIM + segk;
  const u16* gB0 = B + (size_t)(col0 + segr) * DDIM + segk;
  const u16* gB1 = B + (size_t)(col0 + 64 + segr) * DDIM + segk;

  for (int k0 = 0; k0 < DDIM; k0 += 32) {
    gload_lds16(gA0 + k0, &As[(0 * 256 + t) * 8]);
    gload_lds16(gA1 + k0, &As[(1 * 256 + t) * 8]);
    gload_lds16(gB0 + k0, &Bs[(0 * 256 + t) * 8]);
    gload_lds16(gB1 + k0, &Bs[(1 * 256 + t) * 8]);
    __syncthreads();
    bfrag af[4], bf[4];
#pragma unroll
    for (int mi = 0; mi < 4; mi++) af[mi] = *(const bfrag*)&As[(wm + mi * 16 + r) * 32 + q * 8];
#pragma unroll
    for (int ni = 0; ni < 4; ni++) bf[ni] = *(const bfrag*)&Bs[(wn + ni * 16 + r) * 32 + q * 8];
#pragma unroll
    for (int mi = 0; mi < 4; mi++)
#pragma unroll
      for (int ni = 0; ni < 4; ni++)
        acc[mi][ni] = __builtin_amdgcn_mfma_f32_16x16x32_bf16(af[mi], bf[ni], acc[mi][ni], 0, 0, 0);
    __syncthreads();
  }
#pragma unroll
  for (int mi = 0; mi < 4; mi++)
#pragma unroll
    for (int ni = 0; ni < 4; ni++)
#pragma unroll
      for (int e = 0; e < 4; e++) {
        int rr = row0 + wm + mi * 16 + q * 4 + e;
        int cc = col0 + wn + ni * 16 + r;
        float v = acc[mi][ni][e];
        Gout[(size_t)rr * DDIM + cc] = f2bf(1.0f / (1.0f + __expf(-v)));
      }
}

// ------------------------------ K8: y = gate * (hs @ W_C^T); RMSNorm; write out
__global__ __launch_bounds__(1024) void k_final(const float* __restrict__ hs,
                                                const u16* __restrict__ gate,
                                                const float* __restrict__ WC,
                                                const float* __restrict__ norm_w,
                                                float* __restrict__ out,
                                                int rows_per_block) {
  __shared__ float red[2][16];
  const int t = threadIdx.x;     // t == d (0..1023)
  const int wv = t >> 6;
  float wct[16];
#pragma unroll
  for (int n4 = 0; n4 < 4; n4++) {
    float4 v = *(const float4*)&WC[t * 16 + n4 * 4];
    wct[n4 * 4 + 0] = v.x; wct[n4 * 4 + 1] = v.y;
    wct[n4 * 4 + 2] = v.z; wct[n4 * 4 + 3] = v.w;
  }
  const float nw = norm_w[t];
  const int row0 = blockIdx.x * rows_per_block;
  for (int rr = 0; rr < rows_per_block; rr++) {
    const int row = row0 + rr;
    const float* hp = hs + (size_t)row * 16;
    float4 h0 = *(const float4*)hp;
    float4 h1 = *(const float4*)(hp + 4);
    float4 h2 = *(const float4*)(hp + 8);
    float4 h3 = *(const float4*)(hp + 12);
    float z = wct[0] * h0.x + wct[1] * h0.y + wct[2] * h0.z + wct[3] * h0.w
            + wct[4] * h1.x + wct[5] * h1.y + wct[6] * h1.z + wct[7] * h1.w
            + wct[8] * h2.x + wct[9] * h2.y + wct[10] * h2.z + wct[11] * h2.w
            + wct[12] * h3.x + wct[13] * h3.y + wct[14] * h3.z + wct[15] * h3.w;
    float g = bf2f(gate[(size_t)row * DDIM + t]);
    float y = g * z;
    float p = y * y;
#pragma unroll
    for (int o = 32; o > 0; o >>= 1) p += __shfl_down(p, o, 64);
    const int pb = rr & 1;
    if ((t & 63) == 0) red[pb][wv] = p;
    __syncthreads();
    float tot = 0.0f;
#pragma unroll
    for (int i2 = 0; i2 < 16; i2++) tot += red[pb][i2];
    float inv = 1.0f / sqrtf(tot * (1.0f / 1024.0f) + 1e-6f);
    out[(size_t)row * DDIM + t] = y * inv * nw;
  }
}

// ---------------------------------------------------------------- launcher
extern "C" void kernel_launch(void* const* d_in, const int* in_sizes, int n_in,
                              void* d_out, int out_size, void* d_ws, size_t ws_size,
                              hipStream_t stream) {
  const float* x     = (const float*)d_in[0];
  const float* mask  = (const float*)d_in[1];
  const float* WpR   = (const float*)d_in[2];
  const float* WdR   = (const float*)d_in[3];
  const float* WaR   = (const float*)d_in[4];
  const float* WpL   = (const float*)d_in[5];
  const float* WdL   = (const float*)d_in[6];
  const float* WaL   = (const float*)d_in[7];
  const float* WB    = (const float*)d_in[8];
  const float* WC    = (const float*)d_in[9];
  const float* Wg    = (const float*)d_in[10];
  const float* normw = (const float*)d_in[11];
  // shuffle_perm (d_in[12]) is the deterministic stride transpose; hardcoded in K3.
  float* out = (float*)d_out;
  char* ws = (char*)d_ws;

  // workspace layout (bytes). F/proj/step/comp/hstart are aliased into the gate
  // region: they are fully consumed (K3..K6) before K7 writes gate. Total: ~84.8 MB.
  u16*   xb   = (u16*)(ws + 0);            // 67108864  x as bf16
  u16*   wgb  = (u16*)(ws + 67108864);     //  2097152  W_gate as bf16
  float* hs   = (float*)(ws + 69206016);   //  2097152  scan outputs
  u16*   gate = (u16*)(ws + 71303168);     // 67108864  sigmoid(x Wg^T) as bf16
  u32*   F    = (u32*)(ws + 71303168);     //   262144  argmax packs (aliased)
  float* proj = (float*)(ws + 71565312);   //  6291456  dR/dL/bt        (aliased)
  float* step = (float*)(ws + 77856768);   //  4718592  step operators  (aliased)
  float* comp = (float*)(ws + 82575360);   //    73728  chunk composites(aliased)
  float* hst  = (float*)(ws + 82649088);   //    32768  chunk-start h   (aliased)

  k_cvt_bf16<<<16384, 256, 0, stream>>>(x, xb, 4194304);
  k_cvt_bf16<<<512, 256, 0, stream>>>(Wg, wgb, 131072);
  k_permlogits<<<1024, 256, 0, stream>>>(x, WpR, WpL, F);
  k_proj<<<512, 256, 0, stream>>>(x, WdR, WaR, WdL, WaL, WB, mask, proj);
  k_combine<<<128, 256, 0, stream>>>(F, proj, step);
  k_compose<<<8, 64, 0, stream>>>(step, comp);
  k_bscan<<<1, 64, 0, stream>>>(comp, hst);
  k_apply<<<8, 64, 0, stream>>>(step, hst, hs);
  k_gemm<<<dim3(256, 8), 256, 0, stream>>>(xb, wgb, gate);
  k_final<<<256, 1024, 0, stream>>>(hs, gate, WC, normw, out, 128);
}

// Round 3
// 1099.585 us; speedup vs baseline: 1.6840x; 1.3760x over previous
//
#include <hip/hip_runtime.h>
#include <hip/hip_bf16.h>
#include <math.h>
#include <stdint.h>

typedef unsigned int u32;
typedef unsigned long long u64;
typedef unsigned short u16;

#define NROWS 32768   // 8 * 4096
#define DDIM 1024
#define SLEN 4096
#define NBATCH 8
#define CHUNK 64      // scan chunk length
#define NCHUNK (SLEN / CHUNK)          // 64 chunks per batch
#define TOTCHUNK (NBATCH * NCHUNK)     // 512
#define STEP_STRIDE 36                 // floats per (b,s) step record: [g u64][pad][w16][bt16]

__device__ __forceinline__ u16 f2bf(float f) {
  u32 u = __float_as_uint(f);
  u32 r = (u + 0x7FFFu + ((u >> 16) & 1u)) >> 16;
  return (u16)r;
}
__device__ __forceinline__ float bf2f(u16 h) { return __uint_as_float(((u32)h) << 16); }
__device__ __forceinline__ float sigmoidf_(float v) { return 1.0f / (1.0f + expf(-v)); }

typedef __attribute__((address_space(1))) void gvoid_t;
typedef __attribute__((address_space(3))) void svoid_t;
__device__ __forceinline__ void gload_lds16(const void* g, void* l) {
  __builtin_amdgcn_global_load_lds((gvoid_t*)g, (svoid_t*)l, 16, 0, 0);
}

// ---------------------------------------------------------------- K0: fp32 -> bf16
__global__ __launch_bounds__(256) void k_cvt_bf16(const float* __restrict__ src,
                                                  u16* __restrict__ dst, int n8) {
  int i = blockIdx.x * 256 + threadIdx.x;
  if (i >= n8) return;
  const float4* s4 = (const float4*)src;
  float4 a = s4[2 * i], b = s4[2 * i + 1];
  u32 w0 = (u32)f2bf(a.x) | ((u32)f2bf(a.y) << 16);
  u32 w1 = (u32)f2bf(a.z) | ((u32)f2bf(a.w) << 16);
  u32 w2 = (u32)f2bf(b.x) | ((u32)f2bf(b.y) << 16);
  u32 w3 = (u32)f2bf(b.z) | ((u32)f2bf(b.w) << 16);
  ((uint4*)dst)[i] = make_uint4(w0, w1, w2, w3);
}

// ------------------------------------------- K1: fp64 perm logits + sinkhorn + argmax
// 2 rows per thread: the 4 W ds_read_b128 per k now feed 32 fp64 MACs (halved LDS insts/MAC).
// Per-accumulator fp64 summation order over k is IDENTICAL to the R1/R2 passing versions.
#define WS_STRIDE 160
__device__ __forceinline__ unsigned char sinkhorn_pack(const double* accv) {
  double a[16];
#pragma unroll
  for (int e = 0; e < 16; e++) a[e] = accv[e] * 2.0;  // / TAU
  for (int it = 0; it < 5; it++) {
#pragma unroll
    for (int i = 0; i < 4; i++) {   // row lse (axis -1)
      double m = fmax(fmax(a[i * 4], a[i * 4 + 1]), fmax(a[i * 4 + 2], a[i * 4 + 3]));
      double s = exp(a[i * 4] - m) + exp(a[i * 4 + 1] - m) + exp(a[i * 4 + 2] - m) + exp(a[i * 4 + 3] - m);
      double l = m + log(s);
      a[i * 4] -= l; a[i * 4 + 1] -= l; a[i * 4 + 2] -= l; a[i * 4 + 3] -= l;
    }
#pragma unroll
    for (int j = 0; j < 4; j++) {   // col lse (axis -2)
      double m = fmax(fmax(a[j], a[4 + j]), fmax(a[8 + j], a[12 + j]));
      double s = exp(a[j] - m) + exp(a[4 + j] - m) + exp(a[8 + j] - m) + exp(a[12 + j] - m);
      double l = m + log(s);
      a[j] -= l; a[4 + j] -= l; a[8 + j] -= l; a[12 + j] -= l;
    }
  }
  unsigned char pk = 0;
#pragma unroll
  for (int j = 0; j < 4; j++) {   // argmax over i (first max wins, like np.argmax)
    int best = 0; double bv = a[j];
    if (a[4 + j] > bv)  { bv = a[4 + j];  best = 1; }
    if (a[8 + j] > bv)  { bv = a[8 + j];  best = 2; }
    if (a[12 + j] > bv) { bv = a[12 + j]; best = 3; }
    pk |= (unsigned char)(best << (2 * j));
  }
  return pk;
}

__global__ __launch_bounds__(128) void k_permlogits(const float* __restrict__ x,
                                                    const float* __restrict__ WpR,
                                                    const float* __restrict__ WpL,
                                                    u32* __restrict__ Fbuf) {
  __shared__ float xs[32 * 36];
  __shared__ float ws[32 * WS_STRIDE];
  __shared__ unsigned char Ftmp[32 * 8];
  const int t = threadIdx.x;             // 0..127
  const int row0 = blockIdx.x * 32;
  const int blk = t & 7, rp = t >> 3;    // rp 0..15 -> rows 2rp, 2rp+1
  double acc0[16], acc1[16];
#pragma unroll
  for (int e = 0; e < 16; e++) { acc0[e] = 0.0; acc1[e] = 0.0; }

  for (int k0 = 0; k0 < DDIM; k0 += 32) {
    __syncthreads();
#pragma unroll
    for (int it = 0; it < 2; it++) {     // xs: 32x32 floats = 256 float4
      int i = it * 128 + t;
      int r = i >> 3, kc = (i & 7) << 2;
      float4 v = *(const float4*)&x[(size_t)(row0 + r) * DDIM + k0 + kc];
      xs[r * 36 + kc + 0] = v.x; xs[r * 36 + kc + 1] = v.y;
      xs[r * 36 + kc + 2] = v.z; xs[r * 36 + kc + 3] = v.w;
    }
#pragma unroll
    for (int it = 0; it < 8; it++) {     // ws: 128x32 floats = 1024 float4
      int i = it * 128 + t;
      int c = i >> 3, kc = (i & 7) << 2;
      const float* W = (c < 64) ? (WpR + (size_t)c * DDIM) : (WpL + (size_t)(c - 64) * DDIM);
      float4 v = *(const float4*)&W[k0 + kc];
      int base = ((c >> 4) * 20) + (c & 15);
      ws[(kc + 0) * WS_STRIDE + base] = v.x;
      ws[(kc + 1) * WS_STRIDE + base] = v.y;
      ws[(kc + 2) * WS_STRIDE + base] = v.z;
      ws[(kc + 3) * WS_STRIDE + base] = v.w;
    }
    __syncthreads();
#pragma unroll 2
    for (int kk = 0; kk < 32; kk += 4) {
      float4 xv0 = *(const float4*)&xs[(2 * rp) * 36 + kk];
      float4 xv1 = *(const float4*)&xs[(2 * rp + 1) * 36 + kk];
      float xa0[4] = {xv0.x, xv0.y, xv0.z, xv0.w};
      float xa1[4] = {xv1.x, xv1.y, xv1.z, xv1.w};
#pragma unroll
      for (int j = 0; j < 4; j++) {
        int k = kk + j;
        const float* wp = &ws[k * WS_STRIDE + blk * 20];
        float4 w0 = *(const float4*)(wp);
        float4 w1 = *(const float4*)(wp + 4);
        float4 w2 = *(const float4*)(wp + 8);
        float4 w3 = *(const float4*)(wp + 12);
        double xd0 = (double)xa0[j], xd1 = (double)xa1[j];
        acc0[0]  += xd0 * (double)w0.x;  acc0[1]  += xd0 * (double)w0.y;
        acc0[2]  += xd0 * (double)w0.z;  acc0[3]  += xd0 * (double)w0.w;
        acc0[4]  += xd0 * (double)w1.x;  acc0[5]  += xd0 * (double)w1.y;
        acc0[6]  += xd0 * (double)w1.z;  acc0[7]  += xd0 * (double)w1.w;
        acc0[8]  += xd0 * (double)w2.x;  acc0[9]  += xd0 * (double)w2.y;
        acc0[10] += xd0 * (double)w2.z;  acc0[11] += xd0 * (double)w2.w;
        acc0[12] += xd0 * (double)w3.x;  acc0[13] += xd0 * (double)w3.y;
        acc0[14] += xd0 * (double)w3.z;  acc0[15] += xd0 * (double)w3.w;
        acc1[0]  += xd1 * (double)w0.x;  acc1[1]  += xd1 * (double)w0.y;
        acc1[2]  += xd1 * (double)w0.z;  acc1[3]  += xd1 * (double)w0.w;
        acc1[4]  += xd1 * (double)w1.x;  acc1[5]  += xd1 * (double)w1.y;
        acc1[6]  += xd1 * (double)w1.z;  acc1[7]  += xd1 * (double)w1.w;
        acc1[8]  += xd1 * (double)w2.x;  acc1[9]  += xd1 * (double)w2.y;
        acc1[10] += xd1 * (double)w2.z;  acc1[11] += xd1 * (double)w2.w;
        acc1[12] += xd1 * (double)w3.x;  acc1[13] += xd1 * (double)w3.y;
        acc1[14] += xd1 * (double)w3.z;  acc1[15] += xd1 * (double)w3.w;
      }
    }
  }
  Ftmp[(2 * rp) * 8 + blk]     = sinkhorn_pack(acc0);
  Ftmp[(2 * rp + 1) * 8 + blk] = sinkhorn_pack(acc1);
  __syncthreads();
  if (t < 32) {
    u32 lo = (u32)Ftmp[t * 8 + 0] | ((u32)Ftmp[t * 8 + 1] << 8) |
             ((u32)Ftmp[t * 8 + 2] << 16) | ((u32)Ftmp[t * 8 + 3] << 24);
    u32 hi = (u32)Ftmp[t * 8 + 4] | ((u32)Ftmp[t * 8 + 5] << 8) |
             ((u32)Ftmp[t * 8 + 6] << 16) | ((u32)Ftmp[t * 8 + 7] << 24);
    Fbuf[(row0 + t) * 2] = lo;
    Fbuf[(row0 + t) * 2 + 1] = hi;
  }
}

// ------------------------- K2: proj via bf16-split MFMA (fp32-equivalent accuracy)
// C = x @ Wcat^T with x ~= xh+xl, W ~= wh+wl (3 MFMA per tile). Cols: 0-15 WdR,
// 16-31 WaR, 32-47 WdL, 48-63 WaL, 64-79 WB. Epilogue pairing is in-lane.
typedef __attribute__((ext_vector_type(8))) short bfrag;
typedef __attribute__((ext_vector_type(4))) float ffrag;

__device__ __forceinline__ void split8(const float* p, bfrag* hi, bfrag* lo) {
  float4 v0 = *(const float4*)p;
  float4 v1 = *(const float4*)(p + 4);
  float f[8] = {v0.x, v0.y, v0.z, v0.w, v1.x, v1.y, v1.z, v1.w};
#pragma unroll
  for (int e = 0; e < 8; e++) {
    u16 h = f2bf(f[e]);
    (*hi)[e] = (short)h;
    (*lo)[e] = (short)f2bf(f[e] - bf2f(h));
  }
}

__global__ __launch_bounds__(256) void k_proj(const float* __restrict__ x,
                                              const float* __restrict__ WdR, const float* __restrict__ WaR,
                                              const float* __restrict__ WdL, const float* __restrict__ WaL,
                                              const float* __restrict__ WB, const float* __restrict__ mask,
                                              float* __restrict__ proj) {
  __shared__ float xs[64 * 36];      // 64 rows x 32 k (skew 36)
  __shared__ float wsp[80 * 36];     // 80 cols x 32 k (skew 36)
  const int t = threadIdx.x;
  const int wave = t >> 6, lane = t & 63;
  const int r = lane & 15, q = lane >> 4;
  const int row0 = blockIdx.x * 64;
  const int wrow = wave * 16;        // one 16-row m-tile per wave
  ffrag acc[5];
#pragma unroll
  for (int nt = 0; nt < 5; nt++)
#pragma unroll
    for (int e = 0; e < 4; e++) acc[nt][e] = 0.0f;

  for (int k0 = 0; k0 < DDIM; k0 += 32) {
    __syncthreads();
#pragma unroll
    for (int it = 0; it < 2; it++) {   // xs: 64x32 = 512 float4
      int i = it * 256 + t;
      int rr = i >> 3, kc = (i & 7) << 2;
      float4 v = *(const float4*)&x[(size_t)(row0 + rr) * DDIM + k0 + kc];
      xs[rr * 36 + kc + 0] = v.x; xs[rr * 36 + kc + 1] = v.y;
      xs[rr * 36 + kc + 2] = v.z; xs[rr * 36 + kc + 3] = v.w;
    }
#pragma unroll
    for (int it = 0; it < 3; it++) {   // wsp: 80x32 = 640 float4
      int i = it * 256 + t;
      if (i < 640) {
        int c = i >> 3, kc = (i & 7) << 2;
        const float* W = (c < 16) ? WdR + (size_t)c * DDIM
                      : (c < 32) ? WaR + (size_t)(c - 16) * DDIM
                      : (c < 48) ? WdL + (size_t)(c - 32) * DDIM
                      : (c < 64) ? WaL + (size_t)(c - 48) * DDIM
                                 : WB + (size_t)(c - 64) * DDIM;
        float4 v = *(const float4*)&W[k0 + kc];
        wsp[c * 36 + kc + 0] = v.x; wsp[c * 36 + kc + 1] = v.y;
        wsp[c * 36 + kc + 2] = v.z; wsp[c * 36 + kc + 3] = v.w;
      }
    }
    __syncthreads();
    bfrag ah, al;
    split8(&xs[(wrow + r) * 36 + q * 8], &ah, &al);
#pragma unroll
    for (int nt = 0; nt < 5; nt++) {
      bfrag bh, bl;
      split8(&wsp[(nt * 16 + r) * 36 + q * 8], &bh, &bl);
      acc[nt] = __builtin_amdgcn_mfma_f32_16x16x32_bf16(al, bh, acc[nt], 0, 0, 0);
      acc[nt] = __builtin_amdgcn_mfma_f32_16x16x32_bf16(ah, bl, acc[nt], 0, 0, 0);
      acc[nt] = __builtin_amdgcn_mfma_f32_16x16x32_bf16(ah, bh, acc[nt], 0, 0, 0);
    }
  }
#pragma unroll
  for (int e = 0; e < 4; e++) {
    int row = row0 + wrow + q * 4 + e;
    float mv = mask[row];
    float dR = sigmoidf_(acc[1][e]) * tanhf(acc[0][e]);
    float dL = sigmoidf_(acc[3][e]) * tanhf(acc[2][e]);
    float bt = acc[4][e] * mv;
    size_t base = (size_t)row * 48;
    proj[base + r] = dR;
    proj[base + 16 + r] = dL;
    proj[base + 32 + r] = bt;
  }
}

// ----------------- K3: build per-step functional operator: g (packed u64), w[16], bt[16]
__global__ __launch_bounds__(256) void k_combine(const u32* __restrict__ Fbuf,
                                                 const float* __restrict__ proj,
                                                 float* __restrict__ step) {
  __shared__ float lds[256 * 33];
  const int t = threadIdx.x;
  const int row = blockIdx.x * 256 + t;
  float* reg = &lds[t * 33];
  const float* p = proj + (size_t)row * 48;
#pragma unroll
  for (int n = 0; n < 16; n++) reg[n] = p[n];          // dR
#pragma unroll
  for (int n = 0; n < 16; n++) reg[16 + n] = p[16 + n]; // dL
  u32 FRp = Fbuf[row * 2], FLp = Fbuf[row * 2 + 1];
  u64 gp = 0;
  float w[16];
#pragma unroll
  for (int j = 0; j < 16; j++) {
    int r = j >> 2, c = j & 3;
    int i  = (int)((FRp >> (r * 8 + c * 2)) & 3u);  // stage-R dest row within block r
    int k1 = 4 * r + i;
    float wR = reg[k1];
    int i2 = (int)((FLp >> (i * 8 + r * 2)) & 3u);  // stage-L: block i, col r
    int k3 = 4 * i + i2;
    float wL = reg[16 + k3];
    gp |= ((u64)(u32)k3) << (4 * j);
    w[j] = wR * wL;
  }
  float* sp = step + (size_t)row * STEP_STRIDE;
  *(u64*)sp = gp;
#pragma unroll
  for (int j = 0; j < 16; j++) sp[4 + j] = w[j];
#pragma unroll
  for (int n = 0; n < 16; n++) sp[20 + n] = p[32 + n]; // bt (mask already applied)
}

#define LD16F(dst, ptr)                                     \
  {                                                         \
    float4 _a = *(const float4*)((ptr));                    \
    float4 _b = *(const float4*)((ptr) + 4);                \
    float4 _c = *(const float4*)((ptr) + 8);                \
    float4 _d = *(const float4*)((ptr) + 12);               \
    dst[0] = _a.x; dst[1] = _a.y; dst[2] = _a.z; dst[3] = _a.w;   \
    dst[4] = _b.x; dst[5] = _b.y; dst[6] = _b.z; dst[7] = _b.w;   \
    dst[8] = _c.x; dst[9] = _c.y; dst[10] = _c.z; dst[11] = _c.w; \
    dst[12] = _d.x; dst[13] = _d.y; dst[14] = _d.z; dst[15] = _d.w; }

// ------------------------------ K4: per-chunk composition of 64 step operators
__global__ __launch_bounds__(64) void k_compose(const float* __restrict__ step,
                                                float* __restrict__ comp) {
  __shared__ float lds[64 * 34];
  const int t = threadIdx.x;
  const int chunk = blockIdx.x * 64 + t;
  float* Wl = &lds[t * 34];
  float* Tm = Wl + 17;
  const int b = chunk >> 6, c = chunk & 63;
  const size_t base = ((size_t)b * SLEN + (size_t)c * CHUNK) * STEP_STRIDE;
  u64 G = 0xFEDCBA9876543210ull;  // identity map
  float Wc[16], Bc[16];
#pragma unroll
  for (int k = 0; k < 16; k++) { Wc[k] = 1.0f; Bc[k] = 0.0f; }
  for (int s = 0; s < CHUNK; s++) {
    const float* sp = step + base + (size_t)s * STEP_STRIDE;
    u64 gp = *(const u64*)sp;
    float w[16], bt[16];
    LD16F(w, sp + 4);
    LD16F(bt, sp + 20);
#pragma unroll
    for (int n = 0; n < 16; n++) Wl[n] = w[n];
    u64 nG = 0;
#pragma unroll
    for (int k = 0; k < 16; k++) {
      int Gk = (int)((G >> (4 * k)) & 15ull);
      Wc[k] *= Wl[Gk];
      nG |= ((gp >> (4 * Gk)) & 15ull) << (4 * k);
    }
#pragma unroll
    for (int i = 0; i < 16; i++) Tm[i] = bt[i];
#pragma unroll
    for (int j = 0; j < 16; j++) {
      int gj = (int)((gp >> (4 * j)) & 15ull);
      Tm[gj] += w[j] * Bc[j];
    }
#pragma unroll
    for (int i = 0; i < 16; i++) Bc[i] = Tm[i];
    G = nG;
  }
  float* cp = comp + (size_t)chunk * STEP_STRIDE;
  *(u64*)cp = G;
#pragma unroll
  for (int k = 0; k < 16; k++) cp[4 + k] = Wc[k];
#pragma unroll
  for (int k = 0; k < 16; k++) cp[20 + k] = Bc[k];
}

// ---------------------- K5: sequential scan over chunk composites (per batch) -> h at chunk starts
__global__ __launch_bounds__(64) void k_bscan(const float* __restrict__ comp,
                                              float* __restrict__ hstart) {
  __shared__ float lds[64 * 17];
  const int t = threadIdx.x;
  if (t >= NBATCH) return;
  float* Tm = &lds[t * 17];
  float h[16];
#pragma unroll
  for (int i = 0; i < 16; i++) h[i] = 0.0f;
  for (int c = 0; c < NCHUNK; c++) {
    int chunk = t * NCHUNK + c;
    const float* cp = comp + (size_t)chunk * STEP_STRIDE;
    u64 G = *(const u64*)cp;
    float Wc[16], Bc[16];
    LD16F(Wc, cp + 4);
    LD16F(Bc, cp + 20);
    float* hp = hstart + (size_t)chunk * 16;
#pragma unroll
    for (int i = 0; i < 16; i++) hp[i] = h[i];
#pragma unroll
    for (int i = 0; i < 16; i++) Tm[i] = Bc[i];
#pragma unroll
    for (int k = 0; k < 16; k++) {
      int Gk = (int)((G >> (4 * k)) & 15ull);
      Tm[Gk] += Wc[k] * h[k];
    }
#pragma unroll
    for (int i = 0; i < 16; i++) h[i] = Tm[i];
  }
}

// ------------------------------ K6: re-apply steps within each chunk, emit hs[row*16]
__global__ __launch_bounds__(64) void k_apply(const float* __restrict__ step,
                                              const float* __restrict__ hstart,
                                              float* __restrict__ hs) {
  __shared__ float lds[64 * 17];
  const int t = threadIdx.x;
  const int chunk = blockIdx.x * 64 + t;
  float* Tm = &lds[t * 17];
  const int b = chunk >> 6, c = chunk & 63;
  const size_t srow = (size_t)b * SLEN + (size_t)c * CHUNK;
  float h[16];
  {
    const float* hp = hstart + (size_t)chunk * 16;
    LD16F(h, hp);
  }
  for (int s = 0; s < CHUNK; s++) {
    const float* sp = step + (srow + s) * STEP_STRIDE;
    u64 gp = *(const u64*)sp;
    float w[16], bt[16];
    LD16F(w, sp + 4);
    LD16F(bt, sp + 20);
#pragma unroll
    for (int i = 0; i < 16; i++) Tm[i] = bt[i];
#pragma unroll
    for (int j = 0; j < 16; j++) {
      int gj = (int)((gp >> (4 * j)) & 15ull);
      Tm[gj] += w[j] * h[j];
    }
#pragma unroll
    for (int i = 0; i < 16; i++) h[i] = Tm[i];
    float* op = hs + (srow + s) * 16;
    float4 v0 = make_float4(h[0], h[1], h[2], h[3]);
    float4 v1 = make_float4(h[4], h[5], h[6], h[7]);
    float4 v2 = make_float4(h[8], h[9], h[10], h[11]);
    float4 v3 = make_float4(h[12], h[13], h[14], h[15]);
    *(float4*)(op) = v0; *(float4*)(op + 4) = v1;
    *(float4*)(op + 8) = v2; *(float4*)(op + 12) = v3;
  }
}

// ------------------------------ K7: bf16 MFMA GEMM gate = sigmoid(x @ Wgate^T), store bf16
__global__ __launch_bounds__(256) void k_gemm(const u16* __restrict__ A,
                                              const u16* __restrict__ B,
                                              u16* __restrict__ Gout) {
  __shared__ u16 As[128 * 32];
  __shared__ u16 Bs[128 * 32];
  const int t = threadIdx.x;
  const int wave = t >> 6, lane = t & 63;
  const int wm = (wave & 1) << 6, wn = (wave >> 1) << 6;
  const int r = lane & 15, q = lane >> 4;
  const int row0 = blockIdx.x << 7, col0 = blockIdx.y << 7;
  ffrag acc[4][4];
#pragma unroll
  for (int mi = 0; mi < 4; mi++)
#pragma unroll
    for (int ni = 0; ni < 4; ni++)
#pragma unroll
      for (int e = 0; e < 4; e++) acc[mi][ni][e] = 0.0f;

  const int segr = t >> 2;             // row within half-tile
  const int segk = (t & 3) << 3;       // k element offset {0,8,16,24}
  const u16* gA0 = A + (size_t)(row0 + segr) * DDIM + segk;
  const u16* gA1 = A + (size_t)(row0 + 64 + segr) * DDIM + segk;
  const u16* gB0 = B + (size_t)(col0 + segr) * DDIM + segk;
  const u16* gB1 = B + (size_t)(col0 + 64 + segr) * DDIM + segk;

  for (int k0 = 0; k0 < DDIM; k0 += 32) {
    gload_lds16(gA0 + k0, &As[(0 * 256 + t) * 8]);
    gload_lds16(gA1 + k0, &As[(1 * 256 + t) * 8]);
    gload_lds16(gB0 + k0, &Bs[(0 * 256 + t) * 8]);
    gload_lds16(gB1 + k0, &Bs[(1 * 256 + t) * 8]);
    __syncthreads();
    bfrag af[4], bf[4];
#pragma unroll
    for (int mi = 0; mi < 4; mi++) af[mi] = *(const bfrag*)&As[(wm + mi * 16 + r) * 32 + q * 8];
#pragma unroll
    for (int ni = 0; ni < 4; ni++) bf[ni] = *(const bfrag*)&Bs[(wn + ni * 16 + r) * 32 + q * 8];
#pragma unroll
    for (int mi = 0; mi < 4; mi++)
#pragma unroll
      for (int ni = 0; ni < 4; ni++)
        acc[mi][ni] = __builtin_amdgcn_mfma_f32_16x16x32_bf16(af[mi], bf[ni], acc[mi][ni], 0, 0, 0);
    __syncthreads();
  }
#pragma unroll
  for (int mi = 0; mi < 4; mi++)
#pragma unroll
    for (int ni = 0; ni < 4; ni++)
#pragma unroll
      for (int e = 0; e < 4; e++) {
        int rr = row0 + wm + mi * 16 + q * 4 + e;
        int cc = col0 + wn + ni * 16 + r;
        float v = acc[mi][ni][e];
        Gout[(size_t)rr * DDIM + cc] = f2bf(1.0f / (1.0f + __expf(-v)));
      }
}

// ------------------------------ K8: y = gate * (hs @ W_C^T); RMSNorm; write out
__global__ __launch_bounds__(1024) void k_final(const float* __restrict__ hs,
                                                const u16* __restrict__ gate,
                                                const float* __restrict__ WC,
                                                const float* __restrict__ norm_w,
                                                float* __restrict__ out,
                                                int rows_per_block) {
  __shared__ float red[2][16];
  const int t = threadIdx.x;     // t == d (0..1023)
  const int wv = t >> 6;
  float wct[16];
#pragma unroll
  for (int n4 = 0; n4 < 4; n4++) {
    float4 v = *(const float4*)&WC[t * 16 + n4 * 4];
    wct[n4 * 4 + 0] = v.x; wct[n4 * 4 + 1] = v.y;
    wct[n4 * 4 + 2] = v.z; wct[n4 * 4 + 3] = v.w;
  }
  const float nw = norm_w[t];
  const int row0 = blockIdx.x * rows_per_block;
  for (int rr = 0; rr < rows_per_block; rr++) {
    const int row = row0 + rr;
    const float* hp = hs + (size_t)row * 16;
    float4 h0 = *(const float4*)hp;
    float4 h1 = *(const float4*)(hp + 4);
    float4 h2 = *(const float4*)(hp + 8);
    float4 h3 = *(const float4*)(hp + 12);
    float z = wct[0] * h0.x + wct[1] * h0.y + wct[2] * h0.z + wct[3] * h0.w
            + wct[4] * h1.x + wct[5] * h1.y + wct[6] * h1.z + wct[7] * h1.w
            + wct[8] * h2.x + wct[9] * h2.y + wct[10] * h2.z + wct[11] * h2.w
            + wct[12] * h3.x + wct[13] * h3.y + wct[14] * h3.z + wct[15] * h3.w;
    float g = bf2f(gate[(size_t)row * DDIM + t]);
    float y = g * z;
    float p = y * y;
#pragma unroll
    for (int o = 32; o > 0; o >>= 1) p += __shfl_down(p, o, 64);
    const int pb = rr & 1;
    if ((t & 63) == 0) red[pb][wv] = p;
    __syncthreads();
    float tot = 0.0f;
#pragma unroll
    for (int i2 = 0; i2 < 16; i2++) tot += red[pb][i2];
    float inv = 1.0f / sqrtf(tot * (1.0f / 1024.0f) + 1e-6f);
    out[(size_t)row * DDIM + t] = y * inv * nw;
  }
}

// ---------------------------------------------------------------- launcher
extern "C" void kernel_launch(void* const* d_in, const int* in_sizes, int n_in,
                              void* d_out, int out_size, void* d_ws, size_t ws_size,
                              hipStream_t stream) {
  const float* x     = (const float*)d_in[0];
  const float* mask  = (const float*)d_in[1];
  const float* WpR   = (const float*)d_in[2];
  const float* WdR   = (const float*)d_in[3];
  const float* WaR   = (const float*)d_in[4];
  const float* WpL   = (const float*)d_in[5];
  const float* WdL   = (const float*)d_in[6];
  const float* WaL   = (const float*)d_in[7];
  const float* WB    = (const float*)d_in[8];
  const float* WC    = (const float*)d_in[9];
  const float* Wg    = (const float*)d_in[10];
  const float* normw = (const float*)d_in[11];
  // shuffle_perm (d_in[12]) is the deterministic stride transpose; hardcoded in K3.
  float* out = (float*)d_out;
  char* ws = (char*)d_ws;

  // workspace layout (bytes). F/proj/step/comp/hstart are aliased into the gate
  // region: they are fully consumed (K3..K6) before K7 writes gate. Total: 132 MB.
  u16*   xb   = (u16*)(ws + 0);            // 67108864  x as bf16
  u16*   wgb  = (u16*)(ws + 67108864);     //  2097152  W_gate as bf16
  float* hs   = (float*)(ws + 69206016);   //  2097152  scan outputs
  u16*   gate = (u16*)(ws + 71303168);     // 67108864  sigmoid(x Wg^T) as bf16
  u32*   F    = (u32*)(ws + 71303168);     //   262144  argmax packs (aliased)
  float* proj = (float*)(ws + 71565312);   //  6291456  dR/dL/bt        (aliased)
  float* step = (float*)(ws + 77856768);   //  4718592  step operators  (aliased)
  float* comp = (float*)(ws + 82575360);   //    73728  chunk composites(aliased)
  float* hst  = (float*)(ws + 82649088);   //    32768  chunk-start h   (aliased)

  k_cvt_bf16<<<16384, 256, 0, stream>>>(x, xb, 4194304);
  k_cvt_bf16<<<512, 256, 0, stream>>>(Wg, wgb, 131072);
  k_permlogits<<<1024, 128, 0, stream>>>(x, WpR, WpL, F);
  k_proj<<<512, 256, 0, stream>>>(x, WdR, WaR, WdL, WaL, WB, mask, proj);
  k_combine<<<128, 256, 0, stream>>>(F, proj, step);
  k_compose<<<8, 64, 0, stream>>>(step, comp);
  k_bscan<<<1, 64, 0, stream>>>(comp, hst);
  k_apply<<<8, 64, 0, stream>>>(step, hst, hs);
  k_gemm<<<dim3(256, 8), 256, 0, stream>>>(xb, wgb, gate);
  k_final<<<256, 1024, 0, stream>>>(hs, gate, WC, normw, out, 128);
}